// Round 18
// baseline (88.846 us; speedup 1.0000x reference)
//
#include <hip/hip_runtime.h>

#define BB 2048
#define UU 4096
#define NSCANBLK 512            // 4 scan rows per 256-thr block (1 row/wave)

typedef float f32x4 __attribute__((ext_vector_type(4)));

#if __has_builtin(__builtin_amdgcn_fractf)
#define FRACTF(x) __builtin_amdgcn_fractf(x)
#else
#define FRACTF(x) ((x) - floorf(x))
#endif

#if __has_builtin(__builtin_amdgcn_fmed3f)
#define FMED3(a,b,c) __builtin_amdgcn_fmed3f((a),(b),(c))
#else
__device__ __forceinline__ float FMED3(float a, float b, float c) {
    return fmaxf(fminf(a, b), fminf(fmaxf(a, b), c));
}
#endif

// hand-issued VMEM: compiler cannot sink/reorder; waits are our counted vmcnt.
#define LD4(r, p) asm volatile("global_load_dwordx4 %0, %1, off" \
                               : "=v"(r) : "v"(p) : "memory")
#define ST4(p, v) asm volatile("global_store_dwordx4 %0, %1, off" \
                               :: "v"(p), "v"(v) : "memory")
#define WAITV(N)  do { asm volatile("s_waitcnt vmcnt(" #N ")" ::: "memory"); \
                       __builtin_amdgcn_sched_barrier(0); } while (0)

// Scan: one row per wave; chunk = 512 cols; lane l owns f4-groups l and 64+l
// (fully coalesced 1KB per instruction). Serial carry relays via readlane;
// step c' = med3(fract(s), s+A, A), s=d'+c, A=-m' (bit-exact; inactive subst
// d'=1, A=-1 is identity on c in [-1,1)). frames rebuilt from saved carry-in.
__global__ __launch_bounds__(256) void fused_kernel(
    const float* __restrict__ dur,
    const float* __restrict__ speech,
    const float* __restrict__ residual_prev,
    const float* __restrict__ cached_prev,
    const int* __restrict__ unit_len,
    const int* __restrict__ sealed_len,
    const int* __restrict__ committed_prev,
    float* __restrict__ out)
{
    float* mat   = out;
    float* proj  = out + (size_t)BB * UU;
    float* resid = out + 2 * (size_t)BB * UU;
    float* cach  = resid + BB;
    float* comm  = cach + (size_t)BB * UU;

    const int tid = (int)threadIdx.x;

    if (blockIdx.x >= NSCANBLK) {
        // ---------- ew path: one row per block, non-active CHUNKS ----------
        int r = (int)blockIdx.x - NSCANBLK;
        int L = min(unit_len[r], sealed_len[r]); L = max(0, min(L, UU));
        int P = committed_prev[r];               P = max(0, min(P, UU));
        bool own = P < L;
        int ac0 = own ? (P >> 9) : 0;
        int ac1 = own ? ((L + 511) >> 9) : 0;
        size_t base = (size_t)r * UU;
        #pragma unroll
        for (int k2 = 0; k2 < 4; ++k2) {
            int g = (k2 << 8) + tid;                 // f4 group 0..1023
            int c = g >> 7;                          // chunk 0..7
            if (c >= ac0 && c < ac1) continue;       // scan wave owns
            int u0 = g << 2;
            float4 pv = make_float4(0.f, 0.f, 0.f, 0.f);
            if (u0 < P) pv = *reinterpret_cast<const float4*>(cached_prev + base + u0);
            float4 p4, m4;
            p4.x = (u0 + 0 < P) ? pv.x : 0.f;
            p4.y = (u0 + 1 < P) ? pv.y : 0.f;
            p4.z = (u0 + 2 < P) ? pv.z : 0.f;
            p4.w = (u0 + 3 < P) ? pv.w : 0.f;
            m4.x = (u0 + 0 < L) ? p4.x : 0.f;
            m4.y = (u0 + 1 < L) ? p4.y : 0.f;
            m4.z = (u0 + 2 < L) ? p4.z : 0.f;
            m4.w = (u0 + 3 < L) ? p4.w : 0.f;
            *reinterpret_cast<float4*>(mat  + base + u0) = m4;
            *reinterpret_cast<float4*>(proj + base + u0) = p4;
            *reinterpret_cast<float4*>(cach + base + u0) = m4;
        }
        return;
    }

    // ---------------- scan path: 4 independent waves, 1 row each ----------------
    const int l = tid & 63;
    const int r = (int)blockIdx.x * 4 + (tid >> 6);
    int L = min(unit_len[r], sealed_len[r]); L = max(0, min(L, UU));
    int P = committed_prev[r];               P = max(0, min(P, UU));
    const unsigned span = (L > P) ? (unsigned)(L - P) : 0u;
    float carry = residual_prev[r];
    const size_t ro = (size_t)r * UU;
    const int l4 = l << 2;

    if (span) {
        const int ac0 = P >> 9, ac1 = (L + 511) >> 9;
        f32x4 dA0, dA1, sA0, sA1, dB0, dB1, sB0, sB1, cc0, cc1;

        {   // prologue: chunk ac0 (d,s halves + cached halves = 6 loads)
            const float* pd = dur + ro + (ac0 << 9) + l4;
            const float* ps = speech + ro + (ac0 << 9) + l4;
            const float* pc = cached_prev + ro + (ac0 << 9) + l4;
            LD4(dA0, pd); LD4(dA1, pd + 256);
            LD4(sA0, ps); LD4(sA1, ps + 256);
            LD4(cc0, pc); LD4(cc1, pc + 256);
            WAITV(0);
        }

#define PHASE(X, Y) do {                                                      \
        const int base_ = t << 9;                                             \
        if (t + 1 < ac1) {                                                    \
            const float* pd_ = dur + ro + base_ + 512 + l4;                   \
            const float* ps_ = speech + ro + base_ + 512 + l4;                \
            LD4(d##Y##0, pd_); LD4(d##Y##1, pd_ + 256);                       \
            LD4(s##Y##0, ps_); LD4(s##Y##1, ps_ + 256);                       \
            WAITV(10);  /* newest 10 = 6 stores(prev) + these 4 loads */      \
        } else {                                                              \
            WAITV(6);   /* newest 6 = stores(prev); chunk-t loads retired */  \
        }                                                                     \
        float dp_[2][4], Am_[2][4], pcv_[2][4];                               \
        {                                                                     \
            float dd0_[4] = {d##X##0[0], d##X##0[1], d##X##0[2], d##X##0[3]}; \
            float dd1_[4] = {d##X##1[0], d##X##1[1], d##X##1[2], d##X##1[3]}; \
            float ss0_[4] = {s##X##0[0], s##X##0[1], s##X##0[2], s##X##0[3]}; \
            float ss1_[4] = {s##X##1[0], s##X##1[1], s##X##1[2], s##X##1[3]}; \
            pcv_[0][0]=cc0[0]; pcv_[0][1]=cc0[1]; pcv_[0][2]=cc0[2];          \
            pcv_[0][3]=cc0[3]; pcv_[1][0]=cc1[0]; pcv_[1][1]=cc1[1];          \
            pcv_[1][2]=cc1[2]; pcv_[1][3]=cc1[3];                             \
            _Pragma("unroll")                                                 \
            for (int j = 0; j < 4; ++j) {                                     \
                int u0_ = base_ + l4 + j;                                     \
                bool va0_ = (unsigned)(u0_ - P) < span;                       \
                dp_[0][j] = va0_ ? dd0_[j] : 1.0f;                            \
                Am_[0][j] = (va0_ && (ss0_[j] <= 0.5f)) ? 0.0f : -1.0f;       \
                int u1_ = u0_ + 256;                                          \
                bool va1_ = (unsigned)(u1_ - P) < span;                       \
                dp_[1][j] = va1_ ? dd1_[j] : 1.0f;                            \
                Am_[1][j] = (va1_ && (ss1_[j] <= 0.5f)) ? 0.0f : -1.0f;       \
            }                                                                 \
        }                                                                     \
        const int glo_ = max(0, P - base_) >> 2;                              \
        const int ghi_ = (min(512, L - base_) + 3) >> 2;                      \
        float cin0_ = 0.f, cin1_ = 0.f;                                       \
        {   const int hi_ = min(64, ghi_);                                    \
            for (int i = glo_; i < hi_; ++i) {                                \
                cin0_ = (l == i) ? carry : cin0_;                             \
                float cc_ = carry;                                            \
                _Pragma("unroll")                                             \
                for (int j = 0; j < 4; ++j) {                                 \
                    float s_ = dp_[0][j] + cc_;                               \
                    cc_ = FMED3(FRACTF(s_), s_ + Am_[0][j], Am_[0][j]);       \
                }                                                             \
                carry = __int_as_float(                                       \
                    __builtin_amdgcn_readlane(__float_as_int(cc_), i));       \
            }                                                                 \
        }                                                                     \
        {   const int lo_ = max(0, glo_ - 64), hi_ = max(0, ghi_ - 64);       \
            for (int i = lo_; i < hi_; ++i) {                                 \
                cin1_ = (l == i) ? carry : cin1_;                             \
                float cc_ = carry;                                            \
                _Pragma("unroll")                                             \
                for (int j = 0; j < 4; ++j) {                                 \
                    float s_ = dp_[1][j] + cc_;                               \
                    cc_ = FMED3(FRACTF(s_), s_ + Am_[1][j], Am_[1][j]);       \
                }                                                             \
                carry = __int_as_float(                                       \
                    __builtin_amdgcn_readlane(__float_as_int(cc_), i));       \
            }                                                                 \
        }                                                                     \
        _Pragma("unroll")                                                     \
        for (int h = 0; h < 2; ++h) {                                         \
            float c2_ = (h == 0) ? cin0_ : cin1_;                             \
            float pj_[4], mt_[4];                                             \
            _Pragma("unroll")                                                 \
            for (int j = 0; j < 4; ++j) {                                     \
                float s_  = dp_[h][j] + c2_;                                  \
                float t1_ = fmaxf(s_, 0.f);                                   \
                float cc_ = FMED3(FRACTF(s_), s_ + Am_[h][j], Am_[h][j]);     \
                float fv_ = t1_ - cc_;                                        \
                c2_ = cc_;                                                    \
                int u_ = base_ + (h << 8) + l4 + j;                           \
                bool va_ = (unsigned)(u_ - P) < span;                         \
                float p_ = va_ ? fv_ : ((u_ < P) ? pcv_[h][j] : 0.f);         \
                pj_[j] = p_;                                                  \
                mt_[j] = (u_ < L) ? p_ : 0.f;                                 \
            }                                                                 \
            f32x4 m_ = {mt_[0], mt_[1], mt_[2], mt_[3]};                      \
            f32x4 q_ = {pj_[0], pj_[1], pj_[2], pj_[3]};                      \
            float* pm_ = mat  + ro + base_ + (h << 8) + l4;                   \
            float* pp_ = proj + ro + base_ + (h << 8) + l4;                   \
            float* pc_ = cach + ro + base_ + (h << 8) + l4;                   \
            ST4(pm_, m_); ST4(pp_, q_); ST4(pc_, m_);                         \
        }                                                                     \
    } while (0)

        int t = ac0;
        for (;;) {
            PHASE(A, B);
            ++t; if (t >= ac1) break;
            PHASE(B, A);
            ++t; if (t >= ac1) break;
        }
    }

    if (l == 0) {
        resid[r] = carry;
        comm[r]  = (float)L;
    }
}

extern "C" void kernel_launch(void* const* d_in, const int* in_sizes, int n_in,
                              void* d_out, int out_size, void* d_ws, size_t ws_size,
                              hipStream_t stream) {
    const float* dur            = (const float*)d_in[0];
    const float* speech         = (const float*)d_in[1];
    const float* residual_prev  = (const float*)d_in[2];
    const float* cached_prev    = (const float*)d_in[3];
    const int*   unit_len       = (const int*)d_in[4];
    const int*   sealed_len     = (const int*)d_in[5];
    const int*   committed_prev = (const int*)d_in[6];

    fused_kernel<<<NSCANBLK + BB, 256, 0, stream>>>(dur, speech, residual_prev,
                                                    cached_prev, unit_len, sealed_len,
                                                    committed_prev, (float*)d_out);
}